// Round 1
// baseline (536.333 us; speedup 1.0000x reference)
//
#include <hip/hip_runtime.h>

#define B_ 2
#define L_ 2048
#define S_ 2048
#define H_ 8
#define E_ 64

typedef float f32x4 __attribute__((ext_vector_type(4)));
typedef short s16x8 __attribute__((ext_vector_type(8)));
typedef unsigned int u32;
typedef unsigned short u16;

#define ESTRIDE 2064   // bf16 per ebuf row (2048 + 16 pad -> 16B-aligned rows, breaks write conflicts)
#define VSTRIDE 136    // bf16 per vstage row (128 + 8 pad)

// bf16 round-to-nearest-even (inputs are finite, no NaN handling needed)
__device__ __forceinline__ u32 f2bf(float f){
  u32 u = __builtin_bit_cast(u32, f);
  return (u + 0x7fffu + ((u >> 16) & 1u)) >> 16;
}
__device__ __forceinline__ float bf2f(u32 h){
  u32 u = h << 16;
  return __builtin_bit_cast(float, u);
}
__device__ __forceinline__ s16x8 cvt8(f32x4 a, f32x4 b){
  s16x8 r;
  r[0]=(short)f2bf(a[0]); r[1]=(short)f2bf(a[1]); r[2]=(short)f2bf(a[2]); r[3]=(short)f2bf(a[3]);
  r[4]=(short)f2bf(b[0]); r[5]=(short)f2bf(b[1]); r[6]=(short)f2bf(b[2]); r[7]=(short)f2bf(b[3]);
  return r;
}

__launch_bounds__(256, 1)
__global__ void attn_kernel(const float* __restrict__ Q,
                            const float* __restrict__ K,
                            const float* __restrict__ V,
                            const int* __restrict__ maskK,   // (B,S) bool-as-int32, nonzero = missing
                            const int* __restrict__ maskQ,   // (B,L)
                            const int* __restrict__ causal_p,
                            float* __restrict__ outV,
                            float* __restrict__ outA,
                            float* __restrict__ outEnt)
{
  // LDS: 66048 + 17408 + 5120 + 512 + 64 + 2048 = 91200 B -> 1 block/CU
  __shared__ __align__(16) u16 ebuf[16 * ESTRIDE];    // unnormalized exp(s'), bf16
  __shared__ __align__(16) u16 vstage[64 * VSTRIDE];  // V super-tile, transposed [e][j], bf16
  __shared__ __align__(16) u16 pbuf[4 * 16 * 40];     // per-wave P staging for PV A-frag (pad 40)
  __shared__ float lsum[4][16];
  __shared__ float tsum[4][16];
  __shared__ float recipA[16];
  __shared__ __align__(8) unsigned char mkb[2048];    // key-miss mask bytes

  const int tid  = threadIdx.x;
  const int lane = tid & 63;
  const int wv   = tid >> 6;
  const int quad = lane >> 4;
  const int l15  = lane & 15;

  const int i0 = blockIdx.x * 16;
  const int h  = blockIdx.y;
  const int b  = blockIdx.z;

  const int causal   = causal_p[0] != 0;
  const int imax_eff = causal ? (i0 + 15) : (S_ - 1);
  const int nsup     = (imax_eff >> 7) + 1;   // 128-j super-chunks to process

  const float scale = 0.125f; // 1/sqrt(E)

  // ---- init: zero ebuf (covers causally-skipped chunks), stage mask_k as bytes ----
  {
    uint4* ez = (uint4*)ebuf;
    for (int k = tid; k < 16 * ESTRIDE / 8; k += 256) ez[k] = make_uint4(0u, 0u, 0u, 0u);
    const int* mk = maskK + b * S_ + tid * 8;
    u32 w0 = (u32)(mk[0]!=0) | ((u32)(mk[1]!=0)<<8) | ((u32)(mk[2]!=0)<<16) | ((u32)(mk[3]!=0)<<24);
    u32 w1 = (u32)(mk[4]!=0) | ((u32)(mk[5]!=0)<<8) | ((u32)(mk[6]!=0)<<16) | ((u32)(mk[7]!=0)<<24);
    ((uint2*)mkb)[tid] = make_uint2(w0, w1);
  }

  // ---- Q fragments (A-operand: lane holds Q[i = l15][e = quad*8 + 0..7], two e-halves) ----
  s16x8 qf0, qf1;
  {
    const float* qrow = Q + (((size_t)(b * L_ + i0 + l15)) * H_ + h) * E_;
    f32x4 a0 = *(const f32x4*)(qrow + quad * 8);
    f32x4 a1 = *(const f32x4*)(qrow + quad * 8 + 4);
    f32x4 b0 = *(const f32x4*)(qrow + 32 + quad * 8);
    f32x4 b1 = *(const f32x4*)(qrow + 32 + quad * 8 + 4);
    qf0 = cvt8(a0, a1);
    qf1 = cvt8(b0, b1);
  }

  float lacc[4] = {0.f, 0.f, 0.f, 0.f};
  float tacc[4] = {0.f, 0.f, 0.f, 0.f};
  f32x4 uacc[4];
  #pragma unroll
  for (int et = 0; et < 4; ++et) uacc[et] = (f32x4)0.f;

  u32* ebw = (u32*)ebuf;
  u32* pbw = (u32*)(pbuf + wv * (16 * 40));
  const f32x4 zero4 = {0.f, 0.f, 0.f, 0.f};

  for (int sp = 0; sp < nsup; ++sp){
    __syncthreads();
    // ---- cooperative stage V[sp*128 .. +128][:] -> vstage bf16 transposed [e][j] ----
    {
      const int jp = tid >> 2;          // j-pair 0..63
      const int e0 = (tid & 3) << 4;    // e base 0,16,32,48
      const float* v0 = V + (((size_t)(b * S_ + sp * 128 + 2 * jp)) * H_ + h) * E_ + e0;
      const float* v1 = v0 + H_ * E_;
      f32x4 x0 = *(const f32x4*)(v0);
      f32x4 x1 = *(const f32x4*)(v0 + 4);
      f32x4 x2 = *(const f32x4*)(v0 + 8);
      f32x4 x3 = *(const f32x4*)(v0 + 12);
      f32x4 y0 = *(const f32x4*)(v1);
      f32x4 y1 = *(const f32x4*)(v1 + 4);
      f32x4 y2 = *(const f32x4*)(v1 + 8);
      f32x4 y3 = *(const f32x4*)(v1 + 12);
      u32* vsw = (u32*)vstage;
      #pragma unroll
      for (int k = 0; k < 4; ++k){
        vsw[(e0 + k     ) * (VSTRIDE/2) + jp] = f2bf(x0[k]) | (f2bf(y0[k]) << 16);
        vsw[(e0 + 4 + k ) * (VSTRIDE/2) + jp] = f2bf(x1[k]) | (f2bf(y1[k]) << 16);
        vsw[(e0 + 8 + k ) * (VSTRIDE/2) + jp] = f2bf(x2[k]) | (f2bf(y2[k]) << 16);
        vsw[(e0 + 12 + k) * (VSTRIDE/2) + jp] = f2bf(x3[k]) | (f2bf(y3[k]) << 16);
      }
    }
    __syncthreads();

    const int j0c = sp * 128 + wv * 32;   // this wave's 32-j chunk
    if (j0c <= imax_eff){
      // ---- K fragments for both 16-j subtiles (B-operand: lane holds K[j=l15][e=quad*8..]) ----
      const float* kr0 = K + (((size_t)(b * S_ + j0c + l15)) * H_ + h) * E_ + quad * 8;
      const float* kr1 = K + (((size_t)(b * S_ + j0c + 16 + l15)) * H_ + h) * E_ + quad * 8;
      f32x4 ka0 = *(const f32x4*)(kr0);
      f32x4 ka1 = *(const f32x4*)(kr0 + 4);
      f32x4 kb0 = *(const f32x4*)(kr0 + 32);
      f32x4 kb1 = *(const f32x4*)(kr0 + 36);
      f32x4 kc0 = *(const f32x4*)(kr1);
      f32x4 kc1 = *(const f32x4*)(kr1 + 4);
      f32x4 kd0 = *(const f32x4*)(kr1 + 32);
      f32x4 kd1 = *(const f32x4*)(kr1 + 36);

      #pragma unroll
      for (int jt = 0; jt < 2; ++jt){
        s16x8 kf0 = jt ? cvt8(kc0, kc1) : cvt8(ka0, ka1);
        s16x8 kf1 = jt ? cvt8(kd0, kd1) : cvt8(kb0, kb1);
        f32x4 sacc = __builtin_amdgcn_mfma_f32_16x16x32_bf16(qf0, kf0, zero4, 0, 0, 0);
        sacc       = __builtin_amdgcn_mfma_f32_16x16x32_bf16(qf1, kf1, sacc, 0, 0, 0);
        // C-layout: value r -> row i0 + quad*4 + r, col j0c + jt*16 + l15
        const int j   = j0c + jt * 16 + l15;
        const int mkv = mkb[j];
        #pragma unroll
        for (int r = 0; r < 4; ++r){
          const int irow = i0 + quad * 4 + r;
          float sv = sacc[r] * scale;
          bool dead = (mkv != 0) || (causal && (j > irow));
          float e = dead ? 0.f : __expf(sv);
          lacc[r] += e;
          tacc[r] += e * sv;
          u32 hv = f2bf(e);
          int o = __shfl_xor((int)hv, 1);
          if ((lane & 1) == 0){
            u32 pk2 = hv | ((u32)o << 16);
            int row = quad * 4 + r;
            ebw[row * (ESTRIDE/2) + (j >> 1)] = pk2;
            pbw[row * 20 + ((jt * 16 + l15) >> 1)] = pk2;
          }
        }
      }
      // ---- PV: P (LDS round-trip, A-layout) x V-tile (vstage, B-layout), K-dim = 32 j ----
      s16x8 pf = *(const s16x8*)(pbuf + wv * (16 * 40) + l15 * 40 + quad * 8);
      #pragma unroll
      for (int et = 0; et < 4; ++et){
        const s16x8 vf = *(const s16x8*)(vstage + (et * 16 + l15) * VSTRIDE + wv * 32 + quad * 8);
        uacc[et] = __builtin_amdgcn_mfma_f32_16x16x32_bf16(pf, vf, uacc[et], 0, 0, 0);
      }
    }
  }

  __syncthreads();  // all PV reads of vstage done; vstage reusable as Ubuf

  // ---- per-row l,t reduction across the 16 cols of each quad, then across waves ----
  #pragma unroll
  for (int r = 0; r < 4; ++r){
    float l = lacc[r], t = tacc[r];
    #pragma unroll
    for (int off = 1; off < 16; off <<= 1){
      l += __shfl_xor(l, off);
      t += __shfl_xor(t, off);
    }
    if (l15 == 0){ lsum[wv][quad * 4 + r] = l; tsum[wv][quad * 4 + r] = t; }
  }
  // ---- dump per-wave U accumulators for cross-wave reduction (overlay on vstage) ----
  float* Ubuf = (float*)vstage;
  #pragma unroll
  for (int et = 0; et < 4; ++et){
    #pragma unroll
    for (int r = 0; r < 4; ++r){
      Ubuf[(wv * 16 + quad * 4 + r) * 64 + et * 16 + l15] = uacc[et][r];
    }
  }
  __syncthreads();

  if (tid < 16){
    float l = lsum[0][tid] + lsum[1][tid] + lsum[2][tid] + lsum[3][tid];
    float t = tsum[0][tid] + tsum[1][tid] + tsum[2][tid] + tsum[3][tid];
    int qm = maskQ[b * L_ + i0 + tid];
    float rc  = (qm != 0) ? 0.f : (1.f / l);
    float ent = (qm != 0) ? 0.f : (__logf(l) - t / l);   // -sum p ln p with p = e/l
    recipA[tid] = rc;
    outEnt[(size_t)(b * H_ + h) * L_ + i0 + tid] = ent;
  }
  __syncthreads();

  // ---- V output: reduce 4 wave-partials, scale, coalesced f32x4 stores ----
  {
    const int i  = tid >> 4;
    const int e4 = (tid & 15) << 2;
    f32x4 s0 = *(const f32x4*)(Ubuf + (0 * 16 + i) * 64 + e4);
    f32x4 s1 = *(const f32x4*)(Ubuf + (1 * 16 + i) * 64 + e4);
    f32x4 s2 = *(const f32x4*)(Ubuf + (2 * 16 + i) * 64 + e4);
    f32x4 s3 = *(const f32x4*)(Ubuf + (3 * 16 + i) * 64 + e4);
    f32x4 vout = (s0 + s1 + s2 + s3) * recipA[i];
    *(f32x4*)(outV + (((size_t)(b * L_ + i0 + i)) * H_ + h) * E_ + e4) = vout;
  }

  // ---- A output: normalize ebuf rows, fully-coalesced streaming stores ----
  {
    float* arow_base = outA + ((size_t)(b * H_ + h) * L_ + i0) * S_;
    for (int r = 0; r < 16; ++r){
      float rc = recipA[r];
      uint4 pk = *((const uint4*)(ebuf + r * ESTRIDE) + tid);
      f32x4 w0, w1;
      w0[0] = bf2f(pk.x & 0xffffu) * rc;  w0[1] = bf2f(pk.x >> 16) * rc;
      w0[2] = bf2f(pk.y & 0xffffu) * rc;  w0[3] = bf2f(pk.y >> 16) * rc;
      w1[0] = bf2f(pk.z & 0xffffu) * rc;  w1[1] = bf2f(pk.z >> 16) * rc;
      w1[2] = bf2f(pk.w & 0xffffu) * rc;  w1[3] = bf2f(pk.w >> 16) * rc;
      float* dst = arow_base + (size_t)r * S_ + tid * 8;
      *(f32x4*)(dst)     = w0;
      *(f32x4*)(dst + 4) = w1;
    }
  }
}

extern "C" void kernel_launch(void* const* d_in, const int* in_sizes, int n_in,
                              void* d_out, int out_size, void* d_ws, size_t ws_size,
                              hipStream_t stream){
  const float* Q  = (const float*)d_in[0];
  const float* K  = (const float*)d_in[1];
  const float* V  = (const float*)d_in[2];
  const int* mk   = (const int*)d_in[3];
  const int* mq   = (const int*)d_in[4];
  // d_in[5] = pos (arange by construction; causal handled via indices)
  const int* cm   = (const int*)d_in[6];

  float* outV   = (float*)d_out;
  float* outA   = outV + (size_t)B_ * L_ * H_ * E_;
  float* outEnt = outA + (size_t)B_ * H_ * L_ * S_;

  dim3 grid(L_ / 16, H_, B_);
  attn_kernel<<<grid, 256, 0, stream>>>(Q, K, V, mk, mq, cm, outV, outA, outEnt);
}

// Round 3
// 497.439 us; speedup vs baseline: 1.0782x; 1.0782x over previous
//
#include <hip/hip_runtime.h>

#define B_ 2
#define L_ 2048
#define S_ 2048
#define H_ 8
#define E_ 64
#define VSTRIDE 136   // u16 per vstage row (64 data + 4 u32 pad)

typedef float f32x4 __attribute__((ext_vector_type(4)));
typedef short s16x8 __attribute__((ext_vector_type(8)));
typedef unsigned int u32;
typedef unsigned short u16;

__device__ __forceinline__ u32 bc(float f){ return __builtin_bit_cast(u32, f); }
__device__ __forceinline__ float exp2g(float x){ return __builtin_amdgcn_exp2f(x); }

// pack 8 f32 -> 8 bf16 (truncation; plenty of slack vs threshold) via v_perm_b32
__device__ __forceinline__ s16x8 pack8(f32x4 a, f32x4 b){
  union { s16x8 v; u32 w[4]; } r;
  r.w[0] = __builtin_amdgcn_perm(bc(a[1]), bc(a[0]), 0x07060302u);
  r.w[1] = __builtin_amdgcn_perm(bc(a[3]), bc(a[2]), 0x07060302u);
  r.w[2] = __builtin_amdgcn_perm(bc(b[1]), bc(b[0]), 0x07060302u);
  r.w[3] = __builtin_amdgcn_perm(bc(b[3]), bc(b[2]), 0x07060302u);
  return r.v;
}

__device__ __forceinline__ void loadK2(const float* kr, s16x8& f0, s16x8& f1){
  f32x4 a0 = *(const f32x4*)(kr);
  f32x4 a1 = *(const f32x4*)(kr + 4);
  f32x4 b0 = *(const f32x4*)(kr + 32);
  f32x4 b1 = *(const f32x4*)(kr + 36);
  f0 = pack8(a0, a1);
  f1 = pack8(b0, b1);
}

__launch_bounds__(256, 4)
__global__ void attn_kernel(const float* __restrict__ Q,
                            const float* __restrict__ K,
                            const float* __restrict__ V,
                            const int* __restrict__ maskK,   // (B,S) bool-as-int32
                            const int* __restrict__ maskQ,   // (B,L)
                            const int* __restrict__ causal_p,
                            float* __restrict__ outV,
                            float* __restrict__ outA,
                            float* __restrict__ outEnt)
{
  // LDS total ~25.2 KB -> 4 blocks/CU (with 128-VGPR cap from launch_bounds)
  __shared__ __align__(16) u16 vstage[64 * VSTRIDE];  // V tile transposed [e][j] bf16, swizzled
  __shared__ __align__(16) u16 pbuf[4 * 16 * 40];     // per-wave P staging (A-frag roundtrip)
  __shared__ float lsum[4][16];
  __shared__ float tsum[4][16];
  __shared__ float recipA[16];
  __shared__ __align__(8) unsigned char mkb[2048];

  const int tid  = threadIdx.x;
  const int lane = tid & 63;
  const int wv   = tid >> 6;
  const int quad = lane >> 4;
  const int l15  = lane & 15;

  const int i0 = blockIdx.x * 16;
  const int h  = blockIdx.y;
  const int b  = blockIdx.z;

  const int causal   = causal_p[0] != 0;
  const int imax_eff = causal ? (i0 + 15) : (S_ - 1);
  const int nsup     = (imax_eff >> 7) + 1;

  // ---- stage key-miss mask as bytes ----
  {
    const int* mk = maskK + b * S_ + tid * 8;
    u32 w0 = (u32)(mk[0]!=0) | ((u32)(mk[1]!=0)<<8) | ((u32)(mk[2]!=0)<<16) | ((u32)(mk[3]!=0)<<24);
    u32 w1 = (u32)(mk[4]!=0) | ((u32)(mk[5]!=0)<<8) | ((u32)(mk[6]!=0)<<16) | ((u32)(mk[7]!=0)<<24);
    ((uint2*)mkb)[tid] = make_uint2(w0, w1);
  }

  float* const outArow = outA + ((size_t)(b * H_ + h) * L_ + i0) * S_;

  // ---- zero-fill causal upper triangle of A (streaming, overlaps sweep1) ----
  if (causal){
    const int jz = ((imax_eff >> 5) + 1) << 5;
    const f32x4 z4 = {0.f, 0.f, 0.f, 0.f};
    for (int r = 0; r < 16; ++r){
      for (int c = jz + (tid << 2); c < S_; c += 1024)
        *(f32x4*)(outArow + (size_t)r * S_ + c) = z4;
    }
  }

  // ---- Q fragments, pre-scaled by (1/sqrt(E))*log2(e) so scores are in log2 units ----
  s16x8 qf0, qf1;
  {
    const float qs = 0.125f * 1.44269504f;
    const float* qrow = Q + (((size_t)(b * L_ + i0 + l15)) * H_ + h) * E_;
    f32x4 a0 = *(const f32x4*)(qrow + quad * 8)      * qs;
    f32x4 a1 = *(const f32x4*)(qrow + quad * 8 + 4)  * qs;
    f32x4 b0 = *(const f32x4*)(qrow + 32 + quad * 8)     * qs;
    f32x4 b1 = *(const f32x4*)(qrow + 32 + quad * 8 + 4) * qs;
    qf0 = pack8(a0, a1);
    qf1 = pack8(b0, b1);
  }

  const float* const Kbh = K + ((size_t)(b * S_) * H_ + h) * E_;
  const f32x4 zero4 = {0.f, 0.f, 0.f, 0.f};

  __syncthreads();  // mkb visible

  // ================= SWEEP 1: row sums l, t (no stores) =================
  float lacc[4] = {0.f,0.f,0.f,0.f};
  float tacc[4] = {0.f,0.f,0.f,0.f};
  for (int c = wv; (c << 5) <= imax_eff; c += 4){
    const int j0c = c << 5;
    s16x8 k00, k01, k10, k11;
    loadK2(Kbh + (size_t)(j0c + l15) * (H_ * E_) + quad * 8, k00, k01);
    loadK2(Kbh + (size_t)(j0c + 16 + l15) * (H_ * E_) + quad * 8, k10, k11);
    #pragma unroll
    for (int jt = 0; jt < 2; ++jt){
      f32x4 sacc = __builtin_amdgcn_mfma_f32_16x16x32_bf16(qf0, jt ? k10 : k00, zero4, 0, 0, 0);
      sacc       = __builtin_amdgcn_mfma_f32_16x16x32_bf16(qf1, jt ? k11 : k01, sacc, 0, 0, 0);
      const int j   = j0c + (jt << 4) + l15;
      const int mkv = mkb[j];
      #pragma unroll
      for (int r = 0; r < 4; ++r){
        const int irow = i0 + (quad << 2) + r;
        bool dead = (mkv != 0) || (causal && (j > irow));
        float e = dead ? 0.f : exp2g(sacc[r]);
        lacc[r] += e;
        tacc[r] = __builtin_fmaf(e, sacc[r], tacc[r]);
      }
    }
  }

  // ---- reduce l,t across lanes/waves; entropy + recip ----
  #pragma unroll
  for (int r = 0; r < 4; ++r){
    float l = lacc[r], t = tacc[r];
    #pragma unroll
    for (int off = 1; off < 16; off <<= 1){
      l += __shfl_xor(l, off);
      t += __shfl_xor(t, off);
    }
    if (l15 == 0){ lsum[wv][(quad << 2) + r] = l; tsum[wv][(quad << 2) + r] = t; }
  }
  __syncthreads();
  if (tid < 16){
    float l = lsum[0][tid] + lsum[1][tid] + lsum[2][tid] + lsum[3][tid];
    float t = (tsum[0][tid] + tsum[1][tid] + tsum[2][tid] + tsum[3][tid]) * 0.69314718f;
    int qm = maskQ[b * L_ + i0 + tid];
    float rc  = (qm != 0) ? 0.f : (1.f / l);
    float ent = (qm != 0) ? 0.f : (__logf(l) - t / l);
    recipA[tid] = rc;
    outEnt[(size_t)(b * H_ + h) * L_ + i0 + tid] = ent;
  }
  __syncthreads();

  float rq[4];
  #pragma unroll
  for (int r = 0; r < 4; ++r) rq[r] = recipA[(quad << 2) + r];

  // ================= SWEEP 2: normalized A out + PV =================
  f32x4 uacc[4];
  #pragma unroll
  for (int et = 0; et < 4; ++et) uacc[et] = (f32x4)0.f;

  u32* const pbw = (u32*)(pbuf + wv * (16 * 40));

  for (int sp = 0; sp < nsup; ++sp){
    __syncthreads();
    // ---- stage V[sp*128..+128][:] -> vstage bf16 transposed [e][j], granule-rotated ----
    {
      const int jp = tid >> 2;          // j-pair 0..63
      const int a  = tid & 3;           // e-group
      const int e0 = a << 4;
      const float* v0 = V + (((size_t)(b * S_ + sp * 128 + 2 * jp)) * H_ + h) * E_ + e0;
      const float* v1 = v0 + H_ * E_;
      f32x4 x0 = *(const f32x4*)(v0);
      f32x4 x1 = *(const f32x4*)(v0 + 4);
      f32x4 x2 = *(const f32x4*)(v0 + 8);
      f32x4 x3 = *(const f32x4*)(v0 + 12);
      f32x4 y0 = *(const f32x4*)(v1);
      f32x4 y1 = *(const f32x4*)(v1 + 4);
      f32x4 y2 = *(const f32x4*)(v1 + 8);
      f32x4 y3 = *(const f32x4*)(v1 + 12);
      // swizzled u32 col: rotate 16B granule by 4*(row>>4); row>>4 == a for all 16 rows
      const int colsw = ((((jp >> 2) + (a << 2)) & 15) << 2) | (jp & 3);
      u32* vsw = (u32*)vstage;
      #pragma unroll
      for (int k = 0; k < 4; ++k){
        vsw[(e0 + k     ) * (VSTRIDE/2) + colsw] = __builtin_amdgcn_perm(bc(y0[k]), bc(x0[k]), 0x07060302u);
        vsw[(e0 + 4 + k ) * (VSTRIDE/2) + colsw] = __builtin_amdgcn_perm(bc(y1[k]), bc(x1[k]), 0x07060302u);
        vsw[(e0 + 8 + k ) * (VSTRIDE/2) + colsw] = __builtin_amdgcn_perm(bc(y2[k]), bc(x2[k]), 0x07060302u);
        vsw[(e0 + 12 + k) * (VSTRIDE/2) + colsw] = __builtin_amdgcn_perm(bc(y3[k]), bc(x3[k]), 0x07060302u);
      }
    }
    __syncthreads();

    const int j0c = sp * 128 + wv * 32;
    if (j0c <= imax_eff){
      s16x8 k00, k01, k10, k11;
      loadK2(Kbh + (size_t)(j0c + l15) * (H_ * E_) + quad * 8, k00, k01);
      loadK2(Kbh + (size_t)(j0c + 16 + l15) * (H_ * E_) + quad * 8, k10, k11);
      #pragma unroll
      for (int jt = 0; jt < 2; ++jt){
        f32x4 sacc = __builtin_amdgcn_mfma_f32_16x16x32_bf16(qf0, jt ? k10 : k00, zero4, 0, 0, 0);
        sacc       = __builtin_amdgcn_mfma_f32_16x16x32_bf16(qf1, jt ? k11 : k01, sacc, 0, 0, 0);
        const int j   = j0c + (jt << 4) + l15;
        const int mkv = mkb[j];
        #pragma unroll
        for (int r = 0; r < 4; ++r){
          const int irow = i0 + (quad << 2) + r;
          bool dead = (mkv != 0) || (causal && (j > irow));
          float e = dead ? 0.f : exp2g(sacc[r]);
          // normalized A element, f32-exact, direct store
          outArow[(size_t)((quad << 2) + r) * S_ + j] = e * rq[r];
          // pack unnormalized e (bf16) for the PV A-fragment
          u32 eb = bc(e);
          int o  = __shfl_xor((int)eb, 1);
          if ((lane & 1) == 0){
            pbw[((quad << 2) + r) * 20 + ((jt << 4 | l15) >> 1)] =
              __builtin_amdgcn_perm((u32)o, eb, 0x07060302u);
          }
        }
      }
      // ---- PV: P (LDS roundtrip, A-layout) x V (vstage, B-layout), K=32 ----
      s16x8 pf = *(const s16x8*)(pbuf + wv * (16 * 40) + l15 * 40 + quad * 8);
      #pragma unroll
      for (int et = 0; et < 4; ++et){
        const int gq = ((wv << 2) + quad + (et << 2)) & 15;  // match write-side rotation
        const s16x8 vf = *(const s16x8*)(vstage + (et * 16 + l15) * VSTRIDE + gq * 8);
        uacc[et] = __builtin_amdgcn_mfma_f32_16x16x32_bf16(pf, vf, uacc[et], 0, 0, 0);
      }
    }
  }

  __syncthreads();  // vstage reads done; reuse as Ubuf

  float* Ubuf = (float*)vstage;
  #pragma unroll
  for (int et = 0; et < 4; ++et){
    #pragma unroll
    for (int r = 0; r < 4; ++r){
      Ubuf[(wv * 16 + (quad << 2) + r) * 64 + et * 16 + l15] = uacc[et][r];
    }
  }
  __syncthreads();

  // ---- V output: reduce 4 wave-partials, scale by recip, coalesced stores ----
  {
    const int i  = tid >> 4;
    const int e4 = (tid & 15) << 2;
    f32x4 s0 = *(const f32x4*)(Ubuf + (0 * 16 + i) * 64 + e4);
    f32x4 s1 = *(const f32x4*)(Ubuf + (1 * 16 + i) * 64 + e4);
    f32x4 s2 = *(const f32x4*)(Ubuf + (2 * 16 + i) * 64 + e4);
    f32x4 s3 = *(const f32x4*)(Ubuf + (3 * 16 + i) * 64 + e4);
    f32x4 vout = (s0 + s1 + s2 + s3) * recipA[i];
    *(f32x4*)(outV + (((size_t)(b * L_ + i0 + i)) * H_ + h) * E_ + e4) = vout;
  }
}

extern "C" void kernel_launch(void* const* d_in, const int* in_sizes, int n_in,
                              void* d_out, int out_size, void* d_ws, size_t ws_size,
                              hipStream_t stream){
  const float* Q  = (const float*)d_in[0];
  const float* K  = (const float*)d_in[1];
  const float* V  = (const float*)d_in[2];
  const int* mk   = (const int*)d_in[3];
  const int* mq   = (const int*)d_in[4];
  const int* cm   = (const int*)d_in[6];

  float* outV   = (float*)d_out;
  float* outA   = outV + (size_t)B_ * L_ * H_ * E_;
  float* outEnt = outA + (size_t)B_ * H_ * L_ * S_;

  dim3 grid(L_ / 16, H_, B_);
  attn_kernel<<<grid, 256, 0, stream>>>(Q, K, V, mk, mq, cm, outV, outA, outEnt);
}

// Round 4
// 437.548 us; speedup vs baseline: 1.2258x; 1.1369x over previous
//
#include <hip/hip_runtime.h>

#define B_ 2
#define L_ 2048
#define S_ 2048
#define H_ 8
#define E_ 64
#define VSTRIDE 136   // u16 per vstage row (64 data + 4 u32 pad)

typedef float f32x4 __attribute__((ext_vector_type(4)));
typedef short s16x8 __attribute__((ext_vector_type(8)));
typedef unsigned int u32;
typedef unsigned short u16;

__device__ __forceinline__ u32 bc(float f){ return __builtin_bit_cast(u32, f); }
__device__ __forceinline__ float exp2g(float x){ return __builtin_amdgcn_exp2f(x); }

// pack 8 f32 -> 8 bf16 (truncate-to-bf16 via v_perm; ample slack vs threshold)
__device__ __forceinline__ s16x8 pack8(f32x4 a, f32x4 b){
  union { s16x8 v; u32 w[4]; } r;
  r.w[0] = __builtin_amdgcn_perm(bc(a[1]), bc(a[0]), 0x07060302u);
  r.w[1] = __builtin_amdgcn_perm(bc(a[3]), bc(a[2]), 0x07060302u);
  r.w[2] = __builtin_amdgcn_perm(bc(b[1]), bc(b[0]), 0x07060302u);
  r.w[3] = __builtin_amdgcn_perm(bc(b[3]), bc(b[2]), 0x07060302u);
  return r.v;
}

__device__ __forceinline__ void loadK2(const float* kr, s16x8& f0, s16x8& f1){
  f32x4 a0 = *(const f32x4*)(kr);
  f32x4 a1 = *(const f32x4*)(kr + 4);
  f32x4 b0 = *(const f32x4*)(kr + 32);
  f32x4 b1 = *(const f32x4*)(kr + 36);
  f0 = pack8(a0, a1);
  f1 = pack8(b0, b1);
}

__launch_bounds__(256, 4)
__global__ void attn_kernel(const float* __restrict__ Q,
                            const float* __restrict__ K,
                            const float* __restrict__ V,
                            const int* __restrict__ maskK,
                            const int* __restrict__ maskQ,
                            const int* __restrict__ causal_p,
                            float* __restrict__ outV,
                            float* __restrict__ outA,
                            float* __restrict__ outEnt)
{
  // LDS ~30.8 KB -> >=4 blocks/CU (capped by launch_bounds at 4)
  __shared__ __align__(16) u16 vstage[64 * VSTRIDE];   // V tile [e][j] bf16, swizzled; reused as Ubuf
  __shared__ __align__(16) u16 pbufA[4 * 16 * 40];
  __shared__ __align__(16) u16 pbufB[4 * 16 * 40];
  __shared__ float lsum[4][32];
  __shared__ float tsum[4][32];
  __shared__ float recipS[32];
  __shared__ __align__(8) unsigned char mkb[2048];

  const int tid  = threadIdx.x;
  const int lane = tid & 63;
  const int wv   = tid >> 6;
  const int quad = lane >> 4;
  const int l15  = lane & 15;

  // ---- XCD-aware decode: block n -> XCD n&7; each XCD owns 2 (b,h) slices ----
  const int n   = blockIdx.x;
  const int s   = n >> 3;
  const int bh  = ((n & 7) << 1) | (s >> 6);
  const int b   = bh >> 3;
  const int h   = bh & 7;
  const int iA  = (s & 63) << 4;      // light tile
  const int iB  = 2032 - iA;          // heavy tile; iA+iB const -> balanced blocks

  const int causal = causal_p[0] != 0;
  const int imaxA  = causal ? (iA + 15) : (S_ - 1);
  const int imaxB  = causal ? (iB + 15) : (S_ - 1);
  const int nsup   = (imaxB >> 7) + 1;

  // ---- stage key-miss mask bytes ----
  {
    const int* mk = maskK + b * S_ + tid * 8;
    u32 w0 = (u32)(mk[0]!=0) | ((u32)(mk[1]!=0)<<8) | ((u32)(mk[2]!=0)<<16) | ((u32)(mk[3]!=0)<<24);
    u32 w1 = (u32)(mk[4]!=0) | ((u32)(mk[5]!=0)<<8) | ((u32)(mk[6]!=0)<<16) | ((u32)(mk[7]!=0)<<24);
    ((uint2*)mkb)[tid] = make_uint2(w0, w1);
  }

  float* const outArowA = outA + ((size_t)bh * L_ + iA) * S_;
  float* const outArowB = outA + ((size_t)bh * L_ + iB) * S_;

  // ---- zero-fill causal upper triangles ----
  if (causal){
    const f32x4 z4 = {0.f, 0.f, 0.f, 0.f};
    const int jzA = ((imaxA >> 5) + 1) << 5;
    for (int r = 0; r < 16; ++r)
      for (int c = jzA + (tid << 2); c < S_; c += 1024)
        *(f32x4*)(outArowA + (size_t)r * S_ + c) = z4;
    const int jzB = ((imaxB >> 5) + 1) << 5;
    for (int r = 0; r < 16; ++r)
      for (int c = jzB + (tid << 2); c < S_; c += 1024)
        *(f32x4*)(outArowB + (size_t)r * S_ + c) = z4;
  }

  // ---- Q fragments for both tiles, pre-scaled by (1/sqrt(E))*log2(e) ----
  s16x8 qfA0, qfA1, qfB0, qfB1;
  {
    const float qs = 0.125f * 1.44269504f;
    const float* qa = Q + (((size_t)(b * L_ + iA + l15)) * H_ + h) * E_;
    const float* qb = Q + (((size_t)(b * L_ + iB + l15)) * H_ + h) * E_;
    qfA0 = pack8(*(const f32x4*)(qa + quad*8) * qs,      *(const f32x4*)(qa + quad*8 + 4) * qs);
    qfA1 = pack8(*(const f32x4*)(qa + 32 + quad*8) * qs, *(const f32x4*)(qa + 32 + quad*8 + 4) * qs);
    qfB0 = pack8(*(const f32x4*)(qb + quad*8) * qs,      *(const f32x4*)(qb + quad*8 + 4) * qs);
    qfB1 = pack8(*(const f32x4*)(qb + 32 + quad*8) * qs, *(const f32x4*)(qb + 32 + quad*8 + 4) * qs);
  }

  const float* const Kbh = K + ((size_t)(b * S_) * H_ + h) * E_;
  const f32x4 zero4 = {0.f, 0.f, 0.f, 0.f};

  __syncthreads();  // mkb visible

  // ================= SWEEP 1: row sums l,t for both tiles (shared K loads) =================
  float lA[4] = {0,0,0,0}, tA[4] = {0,0,0,0};
  float lB[4] = {0,0,0,0}, tB[4] = {0,0,0,0};
  for (int c = wv; (c << 5) <= imaxB; c += 4){
    const int j0c = c << 5;
    s16x8 k00, k01, k10, k11;
    loadK2(Kbh + (size_t)(j0c + l15) * (H_ * E_) + quad * 8, k00, k01);
    loadK2(Kbh + (size_t)(j0c + 16 + l15) * (H_ * E_) + quad * 8, k10, k11);
    const bool actA = (j0c <= imaxA);
    #pragma unroll
    for (int jt = 0; jt < 2; ++jt){
      const s16x8 kk0 = jt ? k10 : k00;
      const s16x8 kk1 = jt ? k11 : k01;
      const int j   = j0c + (jt << 4) + l15;
      const int mkv = mkb[j];
      f32x4 sB = __builtin_amdgcn_mfma_f32_16x16x32_bf16(qfB0, kk0, zero4, 0, 0, 0);
      sB       = __builtin_amdgcn_mfma_f32_16x16x32_bf16(qfB1, kk1, sB, 0, 0, 0);
      #pragma unroll
      for (int r = 0; r < 4; ++r){
        const int irow = iB + (quad << 2) + r;
        bool dead = (mkv != 0) || (causal && (j > irow));
        float e = dead ? 0.f : exp2g(sB[r]);
        lB[r] += e;
        tB[r] = __builtin_fmaf(e, sB[r], tB[r]);
      }
      if (actA){
        f32x4 sA = __builtin_amdgcn_mfma_f32_16x16x32_bf16(qfA0, kk0, zero4, 0, 0, 0);
        sA       = __builtin_amdgcn_mfma_f32_16x16x32_bf16(qfA1, kk1, sA, 0, 0, 0);
        #pragma unroll
        for (int r = 0; r < 4; ++r){
          const int irow = iA + (quad << 2) + r;
          bool dead = (mkv != 0) || (causal && (j > irow));
          float e = dead ? 0.f : exp2g(sA[r]);
          lA[r] += e;
          tA[r] = __builtin_fmaf(e, sA[r], tA[r]);
        }
      }
    }
  }

  // ---- reduce l,t; entropy + recip for 32 rows ----
  #pragma unroll
  for (int r = 0; r < 4; ++r){
    float la = lA[r], ta = tA[r], lb = lB[r], tb = tB[r];
    #pragma unroll
    for (int off = 1; off < 16; off <<= 1){
      la += __shfl_xor(la, off);  ta += __shfl_xor(ta, off);
      lb += __shfl_xor(lb, off);  tb += __shfl_xor(tb, off);
    }
    if (l15 == 0){
      lsum[wv][(quad << 2) + r]      = la;  tsum[wv][(quad << 2) + r]      = ta;
      lsum[wv][16 + (quad << 2) + r] = lb;  tsum[wv][16 + (quad << 2) + r] = tb;
    }
  }
  __syncthreads();
  if (tid < 32){
    float l = lsum[0][tid] + lsum[1][tid] + lsum[2][tid] + lsum[3][tid];
    float t = (tsum[0][tid] + tsum[1][tid] + tsum[2][tid] + tsum[3][tid]) * 0.69314718f;
    const int i0t = (tid < 16) ? iA : iB;
    const int row = i0t + (tid & 15);
    int qm = maskQ[b * L_ + row];
    float rc  = (qm != 0) ? 0.f : (1.f / l);
    float ent = (qm != 0) ? 0.f : (__logf(l) - t / l);
    recipS[tid] = rc;
    outEnt[(size_t)bh * L_ + row] = ent;
  }
  __syncthreads();

  float rqA[4], rqB[4];
  #pragma unroll
  for (int r = 0; r < 4; ++r){
    rqA[r] = recipS[(quad << 2) + r];
    rqB[r] = recipS[16 + (quad << 2) + r];
  }

  // ================= SWEEP 2: A out + PV for both tiles =================
  f32x4 uaccA[4], uaccB[4];
  #pragma unroll
  for (int et = 0; et < 4; ++et){ uaccA[et] = (f32x4)0.f; uaccB[et] = (f32x4)0.f; }

  u32* const pbwA = (u32*)(pbufA + wv * (16 * 40));
  u32* const pbwB = (u32*)(pbufB + wv * (16 * 40));

  for (int sp = 0; sp < nsup; ++sp){
    __syncthreads();
    // ---- stage V[sp*128..+128][:] -> vstage bf16 [e][j], granule-rotated ----
    {
      const int jp = tid >> 2;
      const int a  = tid & 3;
      const int e0 = a << 4;
      const float* v0 = V + (((size_t)(b * S_ + sp * 128 + 2 * jp)) * H_ + h) * E_ + e0;
      const float* v1 = v0 + H_ * E_;
      f32x4 x0 = *(const f32x4*)(v0);
      f32x4 x1 = *(const f32x4*)(v0 + 4);
      f32x4 x2 = *(const f32x4*)(v0 + 8);
      f32x4 x3 = *(const f32x4*)(v0 + 12);
      f32x4 y0 = *(const f32x4*)(v1);
      f32x4 y1 = *(const f32x4*)(v1 + 4);
      f32x4 y2 = *(const f32x4*)(v1 + 8);
      f32x4 y3 = *(const f32x4*)(v1 + 12);
      const int colsw = ((((jp >> 2) + (a << 2)) & 15) << 2) | (jp & 3);
      u32* vsw = (u32*)vstage;
      #pragma unroll
      for (int k = 0; k < 4; ++k){
        vsw[(e0 + k     ) * (VSTRIDE/2) + colsw] = __builtin_amdgcn_perm(bc(y0[k]), bc(x0[k]), 0x07060302u);
        vsw[(e0 + 4 + k ) * (VSTRIDE/2) + colsw] = __builtin_amdgcn_perm(bc(y1[k]), bc(x1[k]), 0x07060302u);
        vsw[(e0 + 8 + k ) * (VSTRIDE/2) + colsw] = __builtin_amdgcn_perm(bc(y2[k]), bc(x2[k]), 0x07060302u);
        vsw[(e0 + 12 + k) * (VSTRIDE/2) + colsw] = __builtin_amdgcn_perm(bc(y3[k]), bc(x3[k]), 0x07060302u);
      }
    }
    __syncthreads();

    const int j0c = sp * 128 + wv * 32;
    if (j0c <= imaxB){
      s16x8 k00, k01, k10, k11;
      loadK2(Kbh + (size_t)(j0c + l15) * (H_ * E_) + quad * 8, k00, k01);
      loadK2(Kbh + (size_t)(j0c + 16 + l15) * (H_ * E_) + quad * 8, k10, k11);

      // ---- tile B ----
      #pragma unroll
      for (int jt = 0; jt < 2; ++jt){
        f32x4 sB = __builtin_amdgcn_mfma_f32_16x16x32_bf16(qfB0, jt ? k10 : k00, zero4, 0, 0, 0);
        sB       = __builtin_amdgcn_mfma_f32_16x16x32_bf16(qfB1, jt ? k11 : k01, sB, 0, 0, 0);
        const int j   = j0c + (jt << 4) + l15;
        const int mkv = mkb[j];
        #pragma unroll
        for (int r = 0; r < 4; ++r){
          const int irow = iB + (quad << 2) + r;
          bool dead = (mkv != 0) || (causal && (j > irow));
          float e = dead ? 0.f : exp2g(sB[r]);
          outArowB[(size_t)((quad << 2) + r) * S_ + j] = e * rqB[r];
          u32 eb = bc(e);
          int o  = __shfl_xor((int)eb, 1);
          if ((lane & 1) == 0)
            pbwB[((quad << 2) + r) * 20 + ((jt << 4 | l15) >> 1)] =
              __builtin_amdgcn_perm((u32)o, eb, 0x07060302u);
        }
      }
      {
        s16x8 pf = *(const s16x8*)(pbufB + wv * (16 * 40) + l15 * 40 + quad * 8);
        #pragma unroll
        for (int et = 0; et < 4; ++et){
          const int gq = ((wv << 2) + quad + (et << 2)) & 15;
          const s16x8 vf = *(const s16x8*)(vstage + (et * 16 + l15) * VSTRIDE + gq * 8);
          uaccB[et] = __builtin_amdgcn_mfma_f32_16x16x32_bf16(pf, vf, uaccB[et], 0, 0, 0);
        }
      }

      // ---- tile A ----
      if (j0c <= imaxA){
        #pragma unroll
        for (int jt = 0; jt < 2; ++jt){
          f32x4 sA = __builtin_amdgcn_mfma_f32_16x16x32_bf16(qfA0, jt ? k10 : k00, zero4, 0, 0, 0);
          sA       = __builtin_amdgcn_mfma_f32_16x16x32_bf16(qfA1, jt ? k11 : k01, sA, 0, 0, 0);
          const int j   = j0c + (jt << 4) + l15;
          const int mkv = mkb[j];
          #pragma unroll
          for (int r = 0; r < 4; ++r){
            const int irow = iA + (quad << 2) + r;
            bool dead = (mkv != 0) || (causal && (j > irow));
            float e = dead ? 0.f : exp2g(sA[r]);
            outArowA[(size_t)((quad << 2) + r) * S_ + j] = e * rqA[r];
            u32 eb = bc(e);
            int o  = __shfl_xor((int)eb, 1);
            if ((lane & 1) == 0)
              pbwA[((quad << 2) + r) * 20 + ((jt << 4 | l15) >> 1)] =
                __builtin_amdgcn_perm((u32)o, eb, 0x07060302u);
          }
        }
        s16x8 pf = *(const s16x8*)(pbufA + wv * (16 * 40) + l15 * 40 + quad * 8);
        #pragma unroll
        for (int et = 0; et < 4; ++et){
          const int gq = ((wv << 2) + quad + (et << 2)) & 15;
          const s16x8 vf = *(const s16x8*)(vstage + (et * 16 + l15) * VSTRIDE + gq * 8);
          uaccA[et] = __builtin_amdgcn_mfma_f32_16x16x32_bf16(pf, vf, uaccA[et], 0, 0, 0);
        }
      }
    }
  }

  // ================= epilogue: V outputs for both tiles =================
  float* Ubuf = (float*)vstage;
  __syncthreads();
  #pragma unroll
  for (int et = 0; et < 4; ++et)
    #pragma unroll
    for (int r = 0; r < 4; ++r)
      Ubuf[(wv * 16 + (quad << 2) + r) * 64 + et * 16 + l15] = uaccA[et][r];
  __syncthreads();
  {
    const int i  = tid >> 4;
    const int e4 = (tid & 15) << 2;
    f32x4 s0 = *(const f32x4*)(Ubuf + (0 * 16 + i) * 64 + e4);
    f32x4 s1 = *(const f32x4*)(Ubuf + (1 * 16 + i) * 64 + e4);
    f32x4 s2 = *(const f32x4*)(Ubuf + (2 * 16 + i) * 64 + e4);
    f32x4 s3 = *(const f32x4*)(Ubuf + (3 * 16 + i) * 64 + e4);
    f32x4 vout = (s0 + s1 + s2 + s3) * recipS[i];
    *(f32x4*)(outV + (((size_t)(b * L_ + iA + i)) * H_ + h) * E_ + e4) = vout;
  }
  __syncthreads();
  #pragma unroll
  for (int et = 0; et < 4; ++et)
    #pragma unroll
    for (int r = 0; r < 4; ++r)
      Ubuf[(wv * 16 + (quad << 2) + r) * 64 + et * 16 + l15] = uaccB[et][r];
  __syncthreads();
  {
    const int i  = tid >> 4;
    const int e4 = (tid & 15) << 2;
    f32x4 s0 = *(const f32x4*)(Ubuf + (0 * 16 + i) * 64 + e4);
    f32x4 s1 = *(const f32x4*)(Ubuf + (1 * 16 + i) * 64 + e4);
    f32x4 s2 = *(const f32x4*)(Ubuf + (2 * 16 + i) * 64 + e4);
    f32x4 s3 = *(const f32x4*)(Ubuf + (3 * 16 + i) * 64 + e4);
    f32x4 vout = (s0 + s1 + s2 + s3) * recipS[16 + i];
    *(f32x4*)(outV + (((size_t)(b * L_ + iB + i)) * H_ + h) * E_ + e4) = vout;
  }
}

extern "C" void kernel_launch(void* const* d_in, const int* in_sizes, int n_in,
                              void* d_out, int out_size, void* d_ws, size_t ws_size,
                              hipStream_t stream){
  const float* Q  = (const float*)d_in[0];
  const float* K  = (const float*)d_in[1];
  const float* V  = (const float*)d_in[2];
  const int* mk   = (const int*)d_in[3];
  const int* mq   = (const int*)d_in[4];
  const int* cm   = (const int*)d_in[6];

  float* outV   = (float*)d_out;
  float* outA   = outV + (size_t)B_ * L_ * H_ * E_;
  float* outEnt = outA + (size_t)B_ * H_ * L_ * S_;

  attn_kernel<<<dim3(1024), 256, 0, stream>>>(Q, K, V, mk, mq, cm, outV, outA, outEnt);
}